// Round 7
// baseline (10419.302 us; speedup 1.0000x reference)
//
#include <hip/hip_runtime.h>

typedef _Float16 f16;
typedef _Float16 f16x8 __attribute__((ext_vector_type(8)));
typedef float f32x4 __attribute__((ext_vector_type(4)));

#define T_STEPS 1024
#define BATCH 128
#define HID 512
#define VOC 65
#define DRING 8
#define NLWG 192              // 3 layers * 32 dim-slices * 2 batch-halves
#define NPWG 20               // 4 b-tiles * 5 v-tiles
#define FPAD 16               // ints per flag (64B line)

// workspace layout (bytes)
#define OFF_READY 0           // padded progress flags: [(l*64+bh*32+g)*FPAD], proj at [(192+p)*FPAD]
#define OFF_HRING 32768
#define HRING_BYTES (3*DRING*BATCH*HID*2)            // 3,145,728
#define OFF_WPACK (OFF_HRING + HRING_BYTES)          // 3,178,496
#define WPACK_BYTES (3*32*65536*2)                   // 12,582,912
#define OFF_WOUT (OFF_WPACK + WPACK_BYTES)           // 15,761,408
#define WOUT_BYTES (5*16*512*2)                      // 81,920
#define OFF_EMB (OFF_WOUT + WOUT_BYTES)              // 15,843,328

__device__ __forceinline__ float sigmoidf_(float x){ return 1.0f/(1.0f+__expf(-x)); }
__device__ __forceinline__ float tanhf_(float x){ return 1.0f - 2.0f/(__expf(2.0f*x)+1.0f); }

// coherent 16B load from the LLC (bypass L1+L2)
__device__ __forceinline__ f16x8 ld16_sc(const f16* p) {
  f16x8 r;
  asm volatile("global_load_dwordx4 %0, %1, off sc0 sc1" : "=v"(r) : "v"(p) : "memory");
  return r;
}
__device__ __forceinline__ void st16_sc1(f16* p, f16x8 v){
  asm volatile("global_store_dwordx4 %0, %1, off sc1"::"v"(p),"v"(v):"memory"); }
__device__ __forceinline__ void wait_vm0(){ asm volatile("s_waitcnt vmcnt(0)":::"memory"); }

// NaN-in-any-half detect on a packed f16x8 (exp==0x1F). Legit sums are bounded (|.|<=32).
__device__ __forceinline__ unsigned nan8(f16x8 v){
  union { f16x8 h; unsigned u[4]; } c; c.h = v;
  unsigned bad = 0;
#pragma unroll
  for (int d = 0; d < 4; ++d) {
    unsigned e = c.u[d] & 0x7C007C00u;
    bad |= ((e & 0xFFFFu) == 0x7C00u) | ((e >> 16) == 0x7C00u);
  }
  return bad;
}

// Pack weights FRAG-MAJOR (as round 6) + sentinel-init the h ring:
// slots 0-6 = 0x7FFF (NaN sentinel), slot 7 = 0.0 (h(-1)). sc1 stores -> LLC directly.
__global__ void convert_kernel(const float* __restrict__ emb, const float* __restrict__ w_ih,
                               const float* __restrict__ w_hh, const float* __restrict__ w_out,
                               char* __restrict__ ws) {
  f16* wpack = (f16*)(ws + OFF_WPACK);
  f16* wout  = (f16*)(ws + OFF_WOUT);
  f16* embh  = (f16*)(ws + OFF_EMB);
  unsigned short* hr = (unsigned short*)(ws + OFF_HRING);
  const int NW = 3*32*65536;
  const int HR = 3*DRING*BATCH*HID;                  // 1,572,864
  const int TOT = NW + 40960 + HR + VOC*HID;
  for (int e = blockIdx.x*blockDim.x + threadIdx.x; e < TOT; e += gridDim.x*blockDim.x) {
    if (e < NW) {
      int l = e >> 21, rem = e & 0x1FFFFF;
      int g = rem >> 16, idx = rem & 0xFFFF;
      int gt = idx >> 14, kc = (idx >> 9) & 31, lane = (idx >> 3) & 63, jj = idx & 7;
      int n = lane & 15, q = lane >> 4;
      int k = kc*32 + q*8 + jj, d = g*16 + n;
      int row = (gt==0) ? d : (gt==1) ? 512+d : 1024+d;
      float f = (k < 512) ? w_ih[((size_t)(l*1536+row)<<9) + k]
                          : w_hh[((size_t)(l*1536+row)<<9) + (k-512)];
      f16 h;
      if (gt < 3) h = (f16)f;
      else { f16 hi = (f16)f; h = (f16)((f - (float)hi)*2048.0f); }
      wpack[e] = h;
    } else if (e < NW + 40960) {
      int idx = e - NW;
      int vt = idx >> 13, r2 = idx & 8191;
      int kc = r2 >> 9, lane = (r2 >> 3) & 63, jj = r2 & 7;
      int n = lane & 15, q = lane >> 4;
      int v = vt*16 + n, k = kc*32 + q*8 + jj;
      wout[idx] = (v < VOC) ? (f16)w_out[((size_t)v<<9) + k] : (f16)0.0f;
    } else if (e < NW + 40960 + HR) {
      int idx = e - NW - 40960;
      int slot = (idx >> 16) & 7;                    // per layer: 8 slots x 65536 elems
      unsigned short val = (slot == 7) ? (unsigned short)0u : (unsigned short)0x7FFFu;
      asm volatile("global_store_short %0, %1, off sc1"::"v"(hr + idx),"v"((unsigned)val):"memory");
    } else {
      int idx = e - NW - 40960 - HR;
      embh[idx] = (f16)emb[idx];
    }
  }
}

// Persistent kernel, 212 WGs x 256 threads. Sentinel protocol: producers store h (sc1,
// no drain, no data flags); consumers poll the data (canary chunk, then full load +
// NaN-sum verify). Progress flags (relaxed, every 2 steps) only gate slot recycling.
__global__ void __launch_bounds__(256) rnn_kernel(const int* __restrict__ xseq,
                           const float* __restrict__ bias, const float* __restrict__ bias_n,
                           const float* __restrict__ b_out, float* __restrict__ out,
                           char* __restrict__ ws) {
  int* F = (int*)(ws + OFF_READY);
  f16* hring = (f16*)(ws + OFF_HRING);                // [3][8][128][512]
  const int wg = blockIdx.x;
  const int tid = threadIdx.x;
  const int lane = tid & 63, wv = tid >> 6;
  const int quad = lane >> 4, ko = quad*8, nlane = lane & 15;

  __shared__ __align__(16) f16 wlds[65536];           // 131,072 B
  __shared__ __align__(16) f16 wolds[8192];           // 16,384 B
  __shared__ __align__(16) f16 hstage[64*24];         // 3,072 B

  f16x8 SENT8;
  { union { unsigned short u; f16 h; } sc_; sc_.u = 0x7FFFu;
#pragma unroll
    for (int i = 0; i < 8; ++i) SENT8[i] = sc_.h; }

  if (wg < NLWG) {
    const int l = wg / 64, r = wg % 64, g = r >> 1, bh = r & 1;
    {
      const f16x8* src = (const f16x8*)((const f16*)(ws + OFF_WPACK) + ((size_t)(l*32+g) << 16));
      f16x8* dst = (f16x8*)wlds;
      for (int i = tid; i < 8192; i += 256) dst[i] = src[i];
    }
    const int j = g*16 + nlane;
    const float br  = bias[l*1536 + j];
    const float bz  = bias[l*1536 + 512 + j];
    const float bin = bias[l*1536 + 1024 + j];
    const float bn  = bias_n[l*512 + j];
    const int bm = bh*64 + wv*16 + nlane;             // A-operand batch row

    // wave1: downstream-progress poll (slot-recycle + ring back-pressure gate)
    const int* pollp = F; int pact = 0;
    if (wv == 1) {
      if (l < 2) { if (lane < 32) { pollp = F + ((l+1)*64 + bh*32 + lane)*FPAD; pact = 1; } }
      else       { if (lane < 10) { pollp = F + (192 + bh*10 + lane)*FPAD;      pact = 1; } }
    }
    __syncthreads();
    f16x8 wr[32], wz[32];
#pragma unroll
    for (int kc = 0; kc < 32; ++kc) {
      wr[kc] = *(const f16x8*)(wlds + (((0*32 + kc)*64 + lane) << 3));
      wz[kc] = *(const f16x8*)(wlds + (((1*32 + kc)*64 + lane) << 3));
    }
    const f16* embh = (const f16*)(ws + OFF_EMB);
    unsigned short hprev[4] = {0, 0, 0, 0};

    for (int t = 0; t < T_STEPS; ++t) {
      const int slot_w = t & 7, slot_r = (t + 7) & 7, slot_rs = (t + 2) & 7;
      // downstream progress >= t-3 every 2 steps (needs >= t'-5 at re-sentinel; slack 1)
      if (wv == 1 && (t & 1) == 0) {
        const int tgt = t - 3;
        int spins = 0;
        while (1) {
          int v = 0x7FFFFFFF;
          if (pact) v = __hip_atomic_load(pollp, __ATOMIC_RELAXED, __HIP_MEMORY_SCOPE_AGENT);
          if (__all(v >= tgt)) break;
          if (++spins > (1 << 20)) break;
          __builtin_amdgcn_s_sleep(2);
        }
      }

      const f16* hrk = hring + ((size_t)(l*DRING + slot_r)*BATCH + bm)*HID + ko;
      const f16* xr  = (l > 0)
        ? hring + ((size_t)((l-1)*DRING + slot_w)*BATCH + bm)*HID + ko
        : (const f16*)nullptr;
      f16x8 afr[32];
      if (l == 0) {
        int idx = xseq[bm*T_STEPS + t];
        const f16* xrow = embh + (size_t)idx*HID + ko;
#pragma unroll
        for (int kc = 0; kc < 16; ++kc) afr[kc] = *(const f16x8*)(xrow + kc*32);
      }
      // tier-a: canary poll (chunk 15 of h [+ x]) — caps spin traffic to ~2KB/WG/iter
      {
        int spins = 0;
        while (1) {
          f16x8 ch = ld16_sc(hrk + 15*32);
          f16x8 cx = ch;
          if (l > 0) cx = ld16_sc(xr + 15*32);
          wait_vm0();
          asm volatile("" : "+v"(ch), "+v"(cx));
          f16x8 s = (l > 0) ? (ch + cx) : ch;
          if (!__any(nan8(s))) break;
          if (++spins > (1 << 21)) break;
          __builtin_amdgcn_s_sleep(2);
        }
      }
      // tier-b: full load + NaN-sum verify (TOCTOU-free: verified regs are the operands)
      {
        int spins = 0;
        while (1) {
          if (l > 0) {
#pragma unroll
            for (int kc = 0; kc < 16; ++kc) afr[kc] = ld16_sc(xr + kc*32);
          }
#pragma unroll
          for (int kc = 0; kc < 16; ++kc) afr[16 + kc] = ld16_sc(hrk + kc*32);
          wait_vm0();
#pragma unroll
          for (int kc = 0; kc < 32; ++kc) asm volatile("" : "+v"(afr[kc]));
          f16x8 s = afr[16];
#pragma unroll
          for (int kc = 17; kc < 32; ++kc) s = s + afr[kc];
          if (l > 0) {
#pragma unroll
            for (int kc = 0; kc < 16; ++kc) s = s + afr[kc];
          }
          if (!__any(nan8(s))) break;
          if (++spins > (1 << 20)) break;
          __builtin_amdgcn_s_sleep(2);
        }
      }
      // re-sentinel slot (t-6): rows 2g,2g+1 — gated by this wave's own h-validation
      // (peers' h(t-1) visible => their step-(t-3) sentinel stores drained) + downstream flag
      if (wv == (g >> 3)) {
        int row = bh*64 + 2*g + (lane >> 5);
        f16* p = hring + ((size_t)(l*DRING + slot_rs)*BATCH + row)*HID + (lane & 31)*16;
        st16_sc1(p, SENT8);
        st16_sc1(p + 8, SENT8);
      }

      f32x4 ar{0,0,0,0}, az{0,0,0,0}, anxh{0,0,0,0}, anxl{0,0,0,0}, anhh{0,0,0,0}, anhl{0,0,0,0};
#pragma unroll
      for (int kc = 0; kc < 32; ++kc) {
        f16x8 wnh = *(const f16x8*)(wlds + (((2*32 + kc)*64 + lane) << 3));
        f16x8 wnl = *(const f16x8*)(wlds + (((3*32 + kc)*64 + lane) << 3));
        ar = __builtin_amdgcn_mfma_f32_16x16x32_f16(afr[kc], wr[kc], ar, 0, 0, 0);
        az = __builtin_amdgcn_mfma_f32_16x16x32_f16(afr[kc], wz[kc], az, 0, 0, 0);
        if (kc < 16) {
          anxh = __builtin_amdgcn_mfma_f32_16x16x32_f16(afr[kc], wnh, anxh, 0, 0, 0);
          anxl = __builtin_amdgcn_mfma_f32_16x16x32_f16(afr[kc], wnl, anxl, 0, 0, 0);
        } else {
          anhh = __builtin_amdgcn_mfma_f32_16x16x32_f16(afr[kc], wnh, anhh, 0, 0, 0);
          anhl = __builtin_amdgcn_mfma_f32_16x16x32_f16(afr[kc], wnl, anhl, 0, 0, 0);
        }
      }
#pragma unroll
      for (int i = 0; i < 4; ++i) {
        float rr = sigmoidf_(ar[i] + br);
        float zz = sigmoidf_(az[i] + bz);
        float hn = anhh[i] + anhl[i]*(1.0f/2048.0f) + bn;
        float nn = tanhf_(anxh[i] + anxl[i]*(1.0f/2048.0f) + bin + rr*hn);
        union { unsigned short u; f16 h; } cr; cr.u = hprev[i];
        float hv = nn + zz*((float)cr.h - nn);
        union { f16 h; unsigned short u; } cw; cw.h = (f16)hv;
        hprev[i] = cw.u;
        hstage[(wv*16 + quad*4 + i)*24 + nlane] = cw.h;
      }
      __syncthreads();
      if (tid < 128) {
        int row = tid >> 1, half = tid & 1;
        f16x8 v8 = *(const f16x8*)(hstage + row*24 + half*8);
        f16* hw = hring + ((size_t)(l*DRING + slot_w)*BATCH + bh*64 + row)*HID + g*16 + half*8;
        st16_sc1(hw, v8);                            // fire-and-forget: data IS the signal
      }
      if (tid == 0 && (t & 1))                       // progress flag (slot recycling only)
        __hip_atomic_store(F + (l*64 + bh*32 + g)*FPAD, t + 1,
                           __ATOMIC_RELAXED, __HIP_MEMORY_SCOPE_AGENT);
      __syncthreads();                               // hstage reuse guard
    }
  } else if (wg < NLWG + NPWG) {
    const int p = wg - NLWG, bt = p / 5, vt = p % 5;
    {
      const f16x8* src = (const f16x8*)((const f16*)(ws + OFF_WOUT) + vt*8192);
      f16x8* dst = (f16x8*)wolds;
      for (int i = tid; i < 1024; i += 256) dst[i] = src[i];
    }
    const int v = vt*16 + nlane;
    const float bo = (v < VOC) ? b_out[v] : 0.0f;
    __syncthreads();
    for (int t = 0; t < T_STEPS; ++t) {
      if (wv < 2) {
        const int bmb = bt*32 + wv*16;
        const f16* hrow = hring + ((size_t)(2*DRING + (t & 7))*BATCH + bmb + nlane)*HID + ko;
        f16x8 af[16];
        {
          int spins = 0;
          while (1) {
            f16x8 ch = ld16_sc(hrow + 15*32);
            wait_vm0();
            asm volatile("" : "+v"(ch));
            if (!__any(nan8(ch))) break;
            if (++spins > (1 << 21)) break;
            __builtin_amdgcn_s_sleep(2);
          }
        }
        {
          int spins = 0;
          while (1) {
#pragma unroll
            for (int kc = 0; kc < 16; ++kc) af[kc] = ld16_sc(hrow + kc*32);
            wait_vm0();
#pragma unroll
            for (int kc = 0; kc < 16; ++kc) asm volatile("" : "+v"(af[kc]));
            f16x8 s = af[0];
#pragma unroll
            for (int kc = 1; kc < 16; ++kc) s = s + af[kc];
            if (!__any(nan8(s))) break;
            if (++spins > (1 << 20)) break;
            __builtin_amdgcn_s_sleep(2);
          }
        }
        f32x4 acc{0,0,0,0};
#pragma unroll
        for (int kc = 0; kc < 16; ++kc) {
          f16x8 w = *(const f16x8*)(wolds + ((kc*64 + lane) << 3));
          acc = __builtin_amdgcn_mfma_f32_16x16x32_f16(af[kc], w, acc, 0, 0, 0);
        }
        if (v < VOC) {
#pragma unroll
          for (int i = 0; i < 4; ++i) {
            int bidx = bmb + quad*4 + i;
            out[((size_t)bidx*T_STEPS + t)*VOC + v] = acc[i] + bo;
          }
        }
      }
      __syncthreads();
      if (tid == 0 && (t & 1))
        __hip_atomic_store(F + (192 + p)*FPAD, t + 1, __ATOMIC_RELAXED, __HIP_MEMORY_SCOPE_AGENT);
      __syncthreads();
    }
  }
}

extern "C" void kernel_launch(void* const* d_in, const int* in_sizes, int n_in,
                              void* d_out, int out_size, void* d_ws, size_t ws_size,
                              hipStream_t stream) {
  const int*   xseq  = (const int*)d_in[0];
  const float* emb   = (const float*)d_in[1];
  const float* w_ih  = (const float*)d_in[2];
  const float* w_hh  = (const float*)d_in[3];
  const float* b     = (const float*)d_in[4];
  const float* b_n   = (const float*)d_in[5];
  const float* w_out = (const float*)d_in[6];
  const float* b_out = (const float*)d_in[7];
  char* ws = (char*)d_ws;

  // zero only the flag page; h-ring sentinel init happens in convert_kernel
  (void)hipMemsetAsync(d_ws, 0, OFF_HRING, stream);
  hipLaunchKernelGGL(convert_kernel, dim3(4096), dim3(256), 0, stream,
                     emb, w_ih, w_hh, w_out, ws);
  hipLaunchKernelGGL(rnn_kernel, dim3(NLWG + NPWG), dim3(256), 0, stream,
                     xseq, b, b_n, b_out, (float*)d_out, ws);
}

// Round 8
// 9909.928 us; speedup vs baseline: 1.0514x; 1.0514x over previous
//
#include <hip/hip_runtime.h>

typedef _Float16 f16;
typedef _Float16 f16x8 __attribute__((ext_vector_type(8)));
typedef float f32x4 __attribute__((ext_vector_type(4)));
typedef unsigned long long u64;

#define T_STEPS 1024
#define BATCH 128
#define HID 512
#define VOC 65
#define DRING 8
#define FPAD 16

// flag page (bytes 0..32767), zeroed every call by kernel_launch:
//   RF   : int at [(grp*32+g)*FPAD], grp = l*2+bh (0..5); proj RFP at [(192+p)*FPAD]
//   LF   : u64 at OFF_LF + (grp*32+g)*16   (local flags, plain-stored, nonce-tagged)
//   NONCE: u64 at OFF_NONCE
#define OFF_LF 16384
#define OFF_NONCE 28672
#define OFF_HRING 32768
#define HRING_BYTES (3*DRING*BATCH*HID*2)            // 3,145,728 (remote ring, sc1)
#define OFF_WPACK (OFF_HRING + HRING_BYTES)          // 3,178,496
#define WPACK_BYTES (3*32*65536*2)                   // 12,582,912
#define OFF_WOUT (OFF_WPACK + WPACK_BYTES)           // 15,761,408
#define WOUT_BYTES (5*16*512*2)                      // 81,920
#define OFF_EMB (OFF_WOUT + WOUT_BYTES)              // 15,843,328
#define EMB_BYTES (VOC*HID*2)                        // 66,560
#define OFF_LRING ((OFF_EMB + EMB_BYTES + 255) & ~255)   // 15,909,888
#define LRING_BYTES (6*DRING*64*HID*2)               // 3,145,728 (local ring, plain)
#define WS_NEED ((size_t)(OFF_LRING + LRING_BYTES))  // ~19.1 MB

__device__ __forceinline__ float sigmoidf_(float x){ return 1.0f/(1.0f+__expf(-x)); }
__device__ __forceinline__ float tanhf_(float x){ return 1.0f - 2.0f/(__expf(2.0f*x)+1.0f); }

// device-coherent 16B load (bypass L1+L2; read from LLC)
__device__ __forceinline__ f16x8 ld16_sc(const f16* p){ f16x8 r;
  asm volatile("global_load_dwordx4 %0, %1, off sc0 sc1":"=v"(r):"v"(p):"memory"); return r; }
// XCD-local 16B load (bypass L1 only; served by this XCD's L2)
__device__ __forceinline__ f16x8 ld16_sc0(const f16* p){ f16x8 r;
  asm volatile("global_load_dwordx4 %0, %1, off sc0":"=v"(r):"v"(p):"memory"); return r; }
__device__ __forceinline__ void st16_sc1(f16* p, f16x8 v){
  asm volatile("global_store_dwordx4 %0, %1, off sc1"::"v"(p),"v"(v):"memory"); }
__device__ __forceinline__ void st16_plain(f16* p, f16x8 v){
  asm volatile("global_store_dwordx4 %0, %1, off"::"v"(p),"v"(v):"memory"); }
__device__ __forceinline__ long long ld8_sc0w(const long long* p){ long long v;   // poll-only (embeds drain)
  asm volatile("global_load_dwordx2 %0, %1, off sc0\n\ts_waitcnt vmcnt(0)":"=v"(v):"v"(p):"memory"); return v; }
__device__ __forceinline__ int ld4_sc1w(const int* p){ int v;                      // poll-only (embeds drain)
  asm volatile("global_load_dword %0, %1, off sc0 sc1\n\ts_waitcnt vmcnt(0)":"=v"(v):"v"(p):"memory"); return v; }
__device__ __forceinline__ void st8_plain(long long* p, long long v){
  asm volatile("global_store_dwordx2 %0, %1, off"::"v"(p),"v"(v):"memory"); }
__device__ __forceinline__ void wait_vm0(){ asm volatile("s_waitcnt vmcnt(0)":::"memory"); }

// Pack weights FRAG-MAJOR: per (layer l, slice g): 4 gate-tiles (r, z, n-hi, n-lo*2048)
// x 32 kc x [64 lanes x 8 f16] so a wave's reads are conflict-free. (unchanged from R6)
__global__ void convert_kernel(const float* __restrict__ emb, const float* __restrict__ w_ih,
                               const float* __restrict__ w_hh, const float* __restrict__ w_out,
                               char* __restrict__ ws) {
  f16* wpack = (f16*)(ws + OFF_WPACK);
  f16* wout  = (f16*)(ws + OFF_WOUT);
  f16* embh  = (f16*)(ws + OFF_EMB);
  const int NW = 3*32*65536;
  const int TOT = NW + 40960 + VOC*HID;
  for (int e = blockIdx.x*blockDim.x + threadIdx.x; e < TOT; e += gridDim.x*blockDim.x) {
    if (e < NW) {
      int l = e >> 21, rem = e & 0x1FFFFF;
      int g = rem >> 16, idx = rem & 0xFFFF;
      int gt = idx >> 14, kc = (idx >> 9) & 31, lane = (idx >> 3) & 63, jj = idx & 7;
      int n = lane & 15, q = lane >> 4;
      int k = kc*32 + q*8 + jj, d = g*16 + n;
      int row = (gt==0) ? d : (gt==1) ? 512+d : 1024+d;
      float f = (k < 512) ? w_ih[((size_t)(l*1536+row)<<9) + k]
                          : w_hh[((size_t)(l*1536+row)<<9) + (k-512)];
      f16 h;
      if (gt < 3) h = (f16)f;
      else { f16 hi = (f16)f; h = (f16)((f - (float)hi)*2048.0f); }
      wpack[e] = h;
    } else if (e < NW + 40960) {
      int idx = e - NW;
      int vt = idx >> 13, r2 = idx & 8191;
      int kc = r2 >> 9, lane = (r2 >> 3) & 63, jj = r2 & 7;
      int n = lane & 15, q = lane >> 4;
      int v = vt*16 + n, k = kc*32 + q*8 + jj;
      wout[idx] = (v < VOC) ? (f16)w_out[((size_t)v<<9) + k] : (f16)0.0f;
    } else {
      int idx = e - NW - 40960;
      embh[idx] = (f16)emb[idx];
    }
  }
}

// Persistent kernel, 256 WGs x 256 threads. Role: G = wg&7, m = wg>>3.
// G<6: layer WG (l=G>>1, bh=G&1, slice g=m<32). G==6,m<20: projection. Else idle.
// Backbone = R6 device-scope protocol (rring sc1 + drained RF). Fast path: if the
// mod-8 placement puts a group on one XCD, producers plain-store h to lring + publish
// nonce-tagged LF after a LOCAL-only drain (waves 0/1), while waves 2/3 independently
// do the rring+RF publication. Consumers try LF (sc0, nonce-checked — stale reads can
// never false-positive); any failure falls back to full RF+rring semantics.
__global__ void __launch_bounds__(256) rnn_kernel(const int* __restrict__ xseq,
                           const float* __restrict__ bias, const float* __restrict__ bias_n,
                           const float* __restrict__ b_out, float* __restrict__ out,
                           char* __restrict__ ws, int use_local) {
  int* F = (int*)ws;
  f16* hring = (f16*)(ws + OFF_HRING);                // [3][8][128][512] device-scope
  f16* lring = (f16*)(ws + OFF_LRING);                // [6][8][64][512] XCD-local
  const int wg = blockIdx.x;
  const int tid = threadIdx.x;
  const int lane = tid & 63, wv = tid >> 6;
  const int quad = lane >> 4, ko = quad*8, nlane = lane & 15;
  const int G = wg & 7, m = wg >> 3;

  // nonce publisher (before staging so it propagates while we stage weights)
  if (wg == 0 && tid == 0 && use_local) {
    u64 v = __builtin_amdgcn_s_memrealtime();
    unsigned nn = (unsigned)(v ^ (v >> 32)) | 1u;
    __hip_atomic_store((u64*)(ws + OFF_NONCE), ((u64)nn << 32) | nn,
                       __ATOMIC_RELAXED, __HIP_MEMORY_SCOPE_AGENT);
  }
  if (G == 7 || (G == 6 && m >= 20)) return;

  __shared__ __align__(16) f16 wlds[65536];           // 131,072 B
  __shared__ __align__(16) f16 wolds[8192];           // 16,384 B
  __shared__ __align__(16) f16 hstage[64*24];         // 3,072 B
  __shared__ int stok[8];                             // 0:mode 1:tokA 2:tokB 3:nonce

  if (G < 6) {
    // ================== layer WG ==================
    const int l = G >> 1, bh = G & 1, g = m, grp = G;
    {
      const f16x8* src = (const f16x8*)((const f16*)(ws + OFF_WPACK) + ((size_t)(l*32+g) << 16));
      f16x8* dst = (f16x8*)wlds;
      for (int i = tid; i < 8192; i += 256) dst[i] = src[i];
    }
    if (tid == 0) {
      stok[0] = 0; stok[1] = 0; stok[2] = 0;
      u64 nv = 0;
      if (use_local) {
        int sp = 0;
        while ((nv = __hip_atomic_load((u64*)(ws + OFF_NONCE), __ATOMIC_RELAXED,
                                       __HIP_MEMORY_SCOPE_AGENT)) == 0ull) {
          if (++sp > (1 << 22)) break;
          __builtin_amdgcn_s_sleep(2);
        }
      }
      stok[3] = (int)(nv >> 32);
    }
    __syncthreads();
    const unsigned nonce = (unsigned)stok[3];

    const int j = g*16 + nlane;
    const float br  = bias[l*1536 + j];
    const float bz  = bias[l*1536 + 512 + j];
    const float bin = bias[l*1536 + 1024 + j];
    const float bn  = bias_n[l*512 + j];
    const int bm = bh*64 + wv*16 + nlane;

    // poll pointers
    const long long* lfp = (const long long*)(ws + OFF_LF + (grp*32 + (lane & 31))*16);
    const int* rfselfp = F + (grp*32 + (lane & 31))*FPAD;
    const int* rfprevp = (l > 0) ? (F + ((grp-2)*32 + (lane & 31))*FPAD) : F;
    const int* pnext = (l < 2) ? (F + ((grp+2)*32 + (lane & 31))*FPAD)
                               : (F + (192 + bh*10 + (lane % 10))*FPAD);
    const int bp_act = (l < 2) ? (lane < 32) : (lane < 10);
    int cprev = 0;                                    // cached prev-layer RF (x-gate)
    int cnext = bp_act ? 0 : 0x7FFFFFFF;              // cached downstream RF (back-pressure)

    f16x8 wr[32], wz[32];
#pragma unroll
    for (int kc = 0; kc < 32; ++kc) {
      wr[kc] = *(const f16x8*)(wlds + (((0*32 + kc)*64 + lane) << 3));
      wz[kc] = *(const f16x8*)(wlds + (((1*32 + kc)*64 + lane) << 3));
    }
    const f16* embh = (const f16*)(ws + OFF_EMB);
    unsigned short hprev[4] = {0, 0, 0, 0};

    for (int t = 0; t < T_STEPS; ++t) {
      const int slot_w = t & 7, slot_r = (t + 7) & 7;
      int mode_local = 0;

      if (wv == 0) {
        // combined gate: lanes 0-31 = h-ready (LF fast / RF fallback); lanes 32-63 = x-ready
        int lf_ok = 0, rf_ok = 0, sat;
        if (lane < 32) sat = 0;
        else           sat = (l == 0) || (cprev >= t + 1);
        int spins = 0;
        while (!__all(sat)) {
          if (!sat) {
            if (lane < 32) {
              if (use_local) {
                long long lfv = ld8_sc0w(lfp);
                if ((unsigned)((u64)lfv >> 32) == nonce && (int)lfv >= t) { lf_ok = 1; sat = 1; }
              }
              if (!sat && (!use_local || (spins & 3) == 3)) {
                if (ld4_sc1w(rfselfp) >= t) { rf_ok = 1; sat = 1; }
              }
            } else {
              cprev = ld4_sc1w(rfprevp);
              if (cprev >= t + 1) sat = 1;
            }
          }
          if (__all(sat)) break;
          if (++spins > (1 << 22)) break;
          __builtin_amdgcn_s_sleep(1);
        }
        u64 bal = __ballot(lf_ok != 0);
        mode_local = ((bal & 0xFFFFFFFFull) == 0xFFFFFFFFull) ? 1 : 0;
        if (!mode_local) {
          // remote mode requires full RF (some lanes may have only seen LF)
          int spins2 = 0;
          int ok = (lane < 32) ? rf_ok : 1;
          while (!__all(ok)) {
            if (!ok && lane < 32 && ld4_sc1w(rfselfp) >= t) ok = 1;
            if (__all(ok)) break;
            if (++spins2 > (1 << 22)) break;
            __builtin_amdgcn_s_sleep(1);
          }
        }
        if (tid == 0) *(volatile int*)&stok[0] = ((t + 1) << 1) | mode_local;
      } else {
        if (wv == 1) {
          // back-pressure (cached): downstream must have finished step t-8
          const int tgt = t - (DRING - 1);
          if (cnext < tgt) {
            int spins = 0;
            while (1) {
              if (cnext < tgt) cnext = bp_act ? ld4_sc1w(pnext) : 0x7FFFFFFF;
              if (__all(cnext >= tgt)) break;
              if (++spins > (1 << 22)) break;
              __builtin_amdgcn_s_sleep(1);
            }
          }
        }
        // pick up wave0's mode decision
        volatile int* mp = &stok[0];
        int w, sp = 0;
        while (((w = *mp) >> 1) != t + 1) { if (++sp > (1 << 24)) break; }
        mode_local = w & 1;
      }
      if (wv == 0) mode_local = (stok[0] >> 1) == (t + 1) ? (stok[0] & 1) : mode_local;

      // ---- load phase ----
      f16x8 afr[32];
      if (l == 0) {
        int idx = xseq[bm*T_STEPS + t];
        const f16* xrow = embh + (size_t)idx*HID + ko;
#pragma unroll
        for (int kc = 0; kc < 16; ++kc) afr[kc] = *(const f16x8*)(xrow + kc*32);
      } else {
        const f16* xr = hring + ((size_t)((l-1)*DRING + slot_w)*BATCH + bm)*HID + ko;
#pragma unroll
        for (int kc = 0; kc < 16; ++kc) afr[kc] = ld16_sc(xr + kc*32);
      }
      if (mode_local) {
        const f16* lh = lring + ((size_t)(grp*DRING + slot_r)*64 + (wv*16 + nlane))*HID + ko;
#pragma unroll
        for (int kc = 0; kc < 16; ++kc) afr[16 + kc] = ld16_sc0(lh + kc*32);
      } else {
        const f16* hrk = hring + ((size_t)(l*DRING + slot_r)*BATCH + bm)*HID + ko;
#pragma unroll
        for (int kc = 0; kc < 16; ++kc) afr[16 + kc] = ld16_sc(hrk + kc*32);
      }
      wait_vm0();
#pragma unroll
      for (int kc = 0; kc < 32; ++kc) asm volatile("" : "+v"(afr[kc]));
      __syncthreads();                                // B2: hstage reuse guard (cheap: all drained)

      f32x4 ar{0,0,0,0}, az{0,0,0,0}, anxh{0,0,0,0}, anxl{0,0,0,0}, anhh{0,0,0,0}, anhl{0,0,0,0};
#pragma unroll
      for (int kc = 0; kc < 32; ++kc) {
        f16x8 wnh = *(const f16x8*)(wlds + (((2*32 + kc)*64 + lane) << 3));
        f16x8 wnl = *(const f16x8*)(wlds + (((3*32 + kc)*64 + lane) << 3));
        ar = __builtin_amdgcn_mfma_f32_16x16x32_f16(afr[kc], wr[kc], ar, 0, 0, 0);
        az = __builtin_amdgcn_mfma_f32_16x16x32_f16(afr[kc], wz[kc], az, 0, 0, 0);
        if (kc < 16) {
          anxh = __builtin_amdgcn_mfma_f32_16x16x32_f16(afr[kc], wnh, anxh, 0, 0, 0);
          anxl = __builtin_amdgcn_mfma_f32_16x16x32_f16(afr[kc], wnl, anxl, 0, 0, 0);
        } else {
          anhh = __builtin_amdgcn_mfma_f32_16x16x32_f16(afr[kc], wnh, anhh, 0, 0, 0);
          anhl = __builtin_amdgcn_mfma_f32_16x16x32_f16(afr[kc], wnl, anhl, 0, 0, 0);
        }
      }
#pragma unroll
      for (int i = 0; i < 4; ++i) {
        float rr = sigmoidf_(ar[i] + br);
        float zz = sigmoidf_(az[i] + bz);
        float hn = anhh[i] + anhl[i]*(1.0f/2048.0f) + bn;
        float nn = tanhf_(anxh[i] + anxl[i]*(1.0f/2048.0f) + bin + rr*hn);
        union { unsigned short u; f16 h; } cr; cr.u = hprev[i];
        float hv = nn + zz*((float)cr.h - nn);
        union { f16 h; unsigned short u; } cw; cw.h = (f16)hv;
        hprev[i] = cw.u;
        hstage[(wv*16 + quad*4 + i)*24 + nlane] = cw.h;
      }
      __syncthreads();                                // B3: hstage visible

      // ---- split tails: waves 0/1 -> local ring + LF; waves 2/3 -> remote ring + RF ----
      if (tid < 128) {
        if (use_local) {
          int row = tid >> 1, half = tid & 1;
          f16x8 v8 = *(const f16x8*)(hstage + row*24 + half*8);
          f16* lw = lring + ((size_t)(grp*DRING + slot_w)*64 + row)*HID + g*16 + half*8;
          st16_plain(lw, v8);
          wait_vm0();                                 // LOCAL drain only — fast
          if (tid == 64) *(volatile int*)&stok[1] = t + 1;
          if (tid == 0) {
            volatile int* ta = &stok[1]; int sp = 0;
            while (*ta != t + 1) { if (++sp > (1 << 24)) break; }
            st8_plain((long long*)(ws + OFF_LF + (grp*32 + g)*16),
                      (long long)(((u64)nonce << 32) | (unsigned)(t + 1)));
          }
        }
      } else {
        int t2 = tid - 128, row = t2 >> 1, half = t2 & 1;
        f16x8 v8 = *(const f16x8*)(hstage + row*24 + half*8);
        f16* hw = hring + ((size_t)(l*DRING + slot_w)*BATCH + bh*64 + row)*HID + g*16 + half*8;
        st16_sc1(hw, v8);
        wait_vm0();                                   // LLC drain — off the local critical path
        if (tid == 192) *(volatile int*)&stok[2] = t + 1;
        if (tid == 128) {
          volatile int* tb = &stok[2]; int sp = 0;
          while (*tb != t + 1) { if (++sp > (1 << 24)) break; }
          __hip_atomic_store(F + (grp*32 + g)*FPAD, t + 1,
                             __ATOMIC_RELAXED, __HIP_MEMORY_SCOPE_AGENT);
        }
      }
    }
  } else {
    // ================== projection WG ==================
    const int p = m, bt = p / 5, vt = p % 5, half = bt >> 1;
    {
      const f16x8* src = (const f16x8*)((const f16*)(ws + OFF_WOUT) + vt*8192);
      f16x8* dst = (f16x8*)wolds;
      for (int i = tid; i < 1024; i += 256) dst[i] = src[i];
    }
    const int v = vt*16 + nlane;
    const float bo = (v < VOC) ? b_out[v] : 0.0f;
    f16* hring2 = (f16*)(ws + OFF_HRING);
    __syncthreads();
    for (int t = 0; t < T_STEPS; ++t) {
      if (wv == 0) {
        const int tgt = t + 1;
        int spins = 0;
        while (1) {
          int vv = 0x7FFFFFFF;
          if (lane < 32) vv = ld4_sc1w(F + ((4 + half)*32 + lane)*FPAD);
          if (__all(vv >= tgt)) break;
          if (++spins > (1 << 22)) break;
          __builtin_amdgcn_s_sleep(1);
        }
      }
      __syncthreads();
      if (wv < 2) {
        const int bmb = bt*32 + wv*16;
        const f16* hrow = hring2 + ((size_t)(2*DRING + (t & 7))*BATCH + bmb + nlane)*HID + ko;
        f16x8 af[16];
#pragma unroll
        for (int kc = 0; kc < 16; ++kc) af[kc] = ld16_sc(hrow + kc*32);
        wait_vm0();
#pragma unroll
        for (int kc = 0; kc < 16; ++kc) asm volatile("" : "+v"(af[kc]));
        f32x4 acc{0,0,0,0};
#pragma unroll
        for (int kc = 0; kc < 16; ++kc) {
          f16x8 w = *(const f16x8*)(wolds + ((kc*64 + lane) << 3));
          acc = __builtin_amdgcn_mfma_f32_16x16x32_f16(af[kc], w, acc, 0, 0, 0);
        }
        if (v < VOC) {
#pragma unroll
          for (int i = 0; i < 4; ++i) {
            int bidx = bmb + quad*4 + i;
            out[((size_t)bidx*T_STEPS + t)*VOC + v] = acc[i] + bo;
          }
        }
      }
      __syncthreads();
      if (tid == 0)
        __hip_atomic_store(F + (192 + p)*FPAD, t + 1, __ATOMIC_RELAXED, __HIP_MEMORY_SCOPE_AGENT);
    }
  }
}

extern "C" void kernel_launch(void* const* d_in, const int* in_sizes, int n_in,
                              void* d_out, int out_size, void* d_ws, size_t ws_size,
                              hipStream_t stream) {
  const int*   xseq  = (const int*)d_in[0];
  const float* emb   = (const float*)d_in[1];
  const float* w_ih  = (const float*)d_in[2];
  const float* w_hh  = (const float*)d_in[3];
  const float* b     = (const float*)d_in[4];
  const float* b_n   = (const float*)d_in[5];
  const float* w_out = (const float*)d_in[6];
  const float* b_out = (const float*)d_in[7];
  char* ws = (char*)d_ws;
  const int use_local = (ws_size >= WS_NEED) ? 1 : 0;

  // zero flag page (incl LF + NONCE) + remote h ring (h[-1]=0); lring needs no init
  (void)hipMemsetAsync(d_ws, 0, OFF_HRING + HRING_BYTES, stream);
  hipLaunchKernelGGL(convert_kernel, dim3(4096), dim3(256), 0, stream,
                     emb, w_ih, w_hh, w_out, ws);
  hipLaunchKernelGGL(rnn_kernel, dim3(256), dim3(256), 0, stream,
                     xseq, b, b_n, b_out, (float*)d_out, ws, use_local);
}

// Round 9
// 9073.060 us; speedup vs baseline: 1.1484x; 1.0922x over previous
//
#include <hip/hip_runtime.h>

typedef _Float16 f16;
typedef _Float16 f16x8 __attribute__((ext_vector_type(8)));
typedef float f32x4 __attribute__((ext_vector_type(4)));

#define T_STEPS 1024
#define BATCH 128
#define HID 512
#define VOC 65
#define DRING 8
#define NLWG 192              // 3 layers * 32 dim-slices * 2 batch-halves
#define NPWG 20               // 4 b-tiles * 5 v-tiles
#define FPAD 8                // ints per flag (32B)

// flag page [0,32KB): per-wave sub-flags SF[(grp*4+wv)*32+g], grp=l*2+bh (0..767)
//                     proj PF at 768+(bh*4+w')*5+vt (768..807)
#define OFF_HRING 32768
#define HRING_BYTES (3*DRING*BATCH*HID*2)            // 3,145,728
#define OFF_WPACK (OFF_HRING + HRING_BYTES)          // 3,178,496
#define WPACK_BYTES (3*32*65536*2)                   // 12,582,912
#define OFF_WOUT (OFF_WPACK + WPACK_BYTES)           // 15,761,408
#define WOUT_BYTES (5*16*512*2)                      // 81,920
#define OFF_EMB (OFF_WOUT + WOUT_BYTES)              // 15,843,328 (+66,560 = 15,909,888 total)

__device__ __forceinline__ float sigmoidf_(float x){ return 1.0f/(1.0f+__expf(-x)); }
__device__ __forceinline__ float tanhf_(float x){ return 1.0f - 2.0f/(__expf(2.0f*x)+1.0f); }

// device-coherent 16B load (read from the coherence point)
__device__ __forceinline__ f16x8 ld16_sc(const f16* p) {
  f16x8 r;
  asm volatile("global_load_dwordx4 %0, %1, off sc0 sc1" : "=v"(r) : "v"(p) : "memory");
  return r;
}
__device__ __forceinline__ void st16_sc1(f16* p, f16x8 v){
  asm volatile("global_store_dwordx4 %0, %1, off sc1"::"v"(p),"v"(v):"memory"); }
__device__ __forceinline__ void wait_vm0(){ asm volatile("s_waitcnt vmcnt(0)":::"memory"); }

// Pack weights FRAG-MAJOR (identical to R6).
__global__ void convert_kernel(const float* __restrict__ emb, const float* __restrict__ w_ih,
                               const float* __restrict__ w_hh, const float* __restrict__ w_out,
                               char* __restrict__ ws) {
  f16* wpack = (f16*)(ws + OFF_WPACK);
  f16* wout  = (f16*)(ws + OFF_WOUT);
  f16* embh  = (f16*)(ws + OFF_EMB);
  const int NW = 3*32*65536;
  const int TOT = NW + 40960 + VOC*HID;
  for (int e = blockIdx.x*blockDim.x + threadIdx.x; e < TOT; e += gridDim.x*blockDim.x) {
    if (e < NW) {
      int l = e >> 21, rem = e & 0x1FFFFF;
      int g = rem >> 16, idx = rem & 0xFFFF;
      int gt = idx >> 14, kc = (idx >> 9) & 31, lane = (idx >> 3) & 63, jj = idx & 7;
      int n = lane & 15, q = lane >> 4;
      int k = kc*32 + q*8 + jj, d = g*16 + n;
      int row = (gt==0) ? d : (gt==1) ? 512+d : 1024+d;
      float f = (k < 512) ? w_ih[((size_t)(l*1536+row)<<9) + k]
                          : w_hh[((size_t)(l*1536+row)<<9) + (k-512)];
      f16 h;
      if (gt < 3) h = (f16)f;
      else { f16 hi = (f16)f; h = (f16)((f - (float)hi)*2048.0f); }
      wpack[e] = h;
    } else if (e < NW + 40960) {
      int idx = e - NW;
      int vt = idx >> 13, r2 = idx & 8191;
      int kc = r2 >> 9, lane = (r2 >> 3) & 63, jj = r2 & 7;
      int n = lane & 15, q = lane >> 4;
      int v = vt*16 + n, k = kc*32 + q*8 + jj;
      wout[idx] = (v < VOC) ? (f16)w_out[((size_t)v<<9) + k] : (f16)0.0f;
    } else {
      int idx = e - NW - 40960;
      embh[idx] = (f16)emb[idx];
    }
  }
}

// Persistent kernel, 212 WGs x 256 threads. BARRIER-FREE step loop:
// producer wave wv owns h rows [wv*16,wv*16+16); consumer wave wv (next layer / proj /
// own group) reads exactly those rows -> per-wave sub-flags, per-wave drains, private
// LDS staging. The 4 waves of a WG never synchronize inside the t-loop.
__global__ void __launch_bounds__(256) rnn_kernel(const int* __restrict__ xseq,
                           const float* __restrict__ bias, const float* __restrict__ bias_n,
                           const float* __restrict__ b_out, float* __restrict__ out,
                           char* __restrict__ ws) {
  int* F = (int*)ws;
  f16* hring = (f16*)(ws + OFF_HRING);                // [3][8][128][512]
  const int wg = blockIdx.x;
  const int tid = threadIdx.x;
  const int lane = tid & 63, wv = tid >> 6;
  const int quad = lane >> 4, ko = quad*8, nlane = lane & 15;

  __shared__ __align__(16) f16 wlds[65536];           // 131,072 B (read-only after stage)
  __shared__ __align__(16) f16 wolds[8192];           // proj W
  __shared__ __align__(16) f16 hstage[64*24];         // per-wave-private rows [wv*16,wv*16+16)

  if (wg < NLWG) {
    const int l = wg / 64, r = wg % 64, g = r >> 1, bh = r & 1;
    const int grp = l*2 + bh;
    {
      const f16x8* src = (const f16x8*)((const f16*)(ws + OFF_WPACK) + ((size_t)(l*32+g) << 16));
      f16x8* dst = (f16x8*)wlds;
      for (int i = tid; i < 8192; i += 256) dst[i] = src[i];
    }
    __syncthreads();                                  // only barrier: wlds ready

    const int j = g*16 + nlane;
    const float br  = bias[l*1536 + j];
    const float bz  = bias[l*1536 + 512 + j];
    const float bin = bias[l*1536 + 1024 + j];
    const float bn  = bias_n[l*512 + j];
    const int bm = bh*64 + wv*16 + nlane;             // this wave's A-operand batch row

    // poll pointers (per lane): lanes 0-31 self-group h, lanes 32-63 upstream x
    const int* sfSelf = F + ((grp*4 + wv)*32 + (lane & 31))*FPAD;
    const int* sfPrev = (l > 0) ? (F + (((grp-2)*4 + wv)*32 + (lane & 31))*FPAD) : F;
    // back-pressure: l<2 -> downstream group same wave (32 flags); l==2 -> proj PF (5 flags)
    const int* bpp; int bp_act;
    if (l < 2) { bpp = F + (((grp+2)*4 + wv)*32 + (lane & 31))*FPAD; bp_act = (lane < 32); }
    else       { bpp = F + (768 + (bh*4 + wv)*5 + (lane % 5))*FPAD;  bp_act = (lane < 5); }
    int cbp = 0;

    f16x8 wr[32], wz[32];
#pragma unroll
    for (int kc = 0; kc < 32; ++kc) {
      wr[kc] = *(const f16x8*)(wlds + (((0*32 + kc)*64 + lane) << 3));
      wz[kc] = *(const f16x8*)(wlds + (((1*32 + kc)*64 + lane) << 3));
    }
    const f16* embh = (const f16*)(ws + OFF_EMB);
    unsigned short hprev[4] = {0, 0, 0, 0};

    for (int t = 0; t < T_STEPS; ++t) {
      const int slot_w = t & 7, slot_r = (t + 7) & 7;

      // back-pressure every 2 steps (cached): downstream >= t-6 (slot-overwrite safety)
      if ((t & 1) == 0) {
        const int tgt = t - 6;
        int ok = bp_act ? (cbp >= tgt) : 1;
        if (!__all(ok)) {
          int sp = 0;
          while (1) {
            if (bp_act && cbp < tgt)
              cbp = __hip_atomic_load(bpp, __ATOMIC_RELAXED, __HIP_MEMORY_SCOPE_AGENT);
            if (__all(bp_act ? (cbp >= tgt) : 1)) break;
            if (++sp > (1 << 22)) break;
            __builtin_amdgcn_s_sleep(1);
          }
        }
      }
      // main gate: h(t-1) from own group-wave (>=t), x(t) from upstream group-wave (>=t+1)
      {
        int sat = (lane < 32) ? 0 : ((l == 0) ? 1 : 0);
        int sp = 0;
        while (1) {
          if (!sat) {
            int v = __hip_atomic_load((lane < 32) ? sfSelf : sfPrev,
                                      __ATOMIC_RELAXED, __HIP_MEMORY_SCOPE_AGENT);
            if (v >= ((lane < 32) ? t : t + 1)) sat = 1;
          }
          if (__all(sat)) break;
          if (++sp > (1 << 22)) break;
          __builtin_amdgcn_s_sleep(1);
        }
      }

      // loads (this wave's 16 rows only)
      f16x8 afr[32];
      if (l == 0) {
        int idx = xseq[bm*T_STEPS + t];
        const f16* xr = embh + (size_t)idx*HID + ko;
#pragma unroll
        for (int kc = 0; kc < 16; ++kc) afr[kc] = *(const f16x8*)(xr + kc*32);
      } else {
        const f16* xr = hring + ((size_t)((l-1)*DRING + slot_w)*BATCH + bm)*HID + ko;
#pragma unroll
        for (int kc = 0; kc < 16; ++kc) afr[kc] = ld16_sc(xr + kc*32);
      }
      {
        const f16* hrk = hring + ((size_t)(l*DRING + slot_r)*BATCH + bm)*HID + ko;
#pragma unroll
        for (int kc = 0; kc < 16; ++kc) afr[16 + kc] = ld16_sc(hrk + kc*32);
      }
      wait_vm0();
#pragma unroll
      for (int kc = 0; kc < 32; ++kc) asm volatile("" : "+v"(afr[kc]));

      f32x4 ar{0,0,0,0}, az{0,0,0,0}, anxh{0,0,0,0}, anxl{0,0,0,0}, anhh{0,0,0,0}, anhl{0,0,0,0};
#pragma unroll
      for (int kc = 0; kc < 32; ++kc) {
        f16x8 wnh = *(const f16x8*)(wlds + (((2*32 + kc)*64 + lane) << 3));
        f16x8 wnl = *(const f16x8*)(wlds + (((3*32 + kc)*64 + lane) << 3));
        ar = __builtin_amdgcn_mfma_f32_16x16x32_f16(afr[kc], wr[kc], ar, 0, 0, 0);
        az = __builtin_amdgcn_mfma_f32_16x16x32_f16(afr[kc], wz[kc], az, 0, 0, 0);
        if (kc < 16) {
          anxh = __builtin_amdgcn_mfma_f32_16x16x32_f16(afr[kc], wnh, anxh, 0, 0, 0);
          anxl = __builtin_amdgcn_mfma_f32_16x16x32_f16(afr[kc], wnl, anxl, 0, 0, 0);
        } else {
          anhh = __builtin_amdgcn_mfma_f32_16x16x32_f16(afr[kc], wnh, anhh, 0, 0, 0);
          anhl = __builtin_amdgcn_mfma_f32_16x16x32_f16(afr[kc], wnl, anhl, 0, 0, 0);
        }
      }
      // epilogue -> private LDS stage (rows wv*16..wv*16+15), intra-wave only
#pragma unroll
      for (int i = 0; i < 4; ++i) {
        float rr = sigmoidf_(ar[i] + br);
        float zz = sigmoidf_(az[i] + bz);
        float hn = anhh[i] + anhl[i]*(1.0f/2048.0f) + bn;
        float nn = tanhf_(anxh[i] + anxl[i]*(1.0f/2048.0f) + bin + rr*hn);
        union { unsigned short u; f16 h; } cr; cr.u = hprev[i];
        float hv = nn + zz*((float)cr.h - nn);
        union { f16 h; unsigned short u; } cw; cw.h = (f16)hv;
        hprev[i] = cw.u;
        hstage[(wv*16 + quad*4 + i)*24 + nlane] = cw.h;
      }
      // wave-local transpose read + coalesced 16B stores (lanes 0-31), no barrier:
      // same-wave DS RAW is ordered by lgkmcnt (compiler-inserted).
      if (lane < 32) {
        int row = wv*16 + (lane >> 1), half = lane & 1;
        f16x8 v8 = *(const f16x8*)(hstage + row*24 + half*8);
        f16* hw = hring + ((size_t)(l*DRING + slot_w)*BATCH + bh*64 + row)*HID + g*16 + half*8;
        st16_sc1(hw, v8);
      }
      wait_vm0();                                     // this wave's stores at coherence point
      if (lane == 0)
        __hip_atomic_store(F + ((grp*4 + wv)*32 + g)*FPAD, t + 1,
                           __ATOMIC_RELAXED, __HIP_MEMORY_SCOPE_AGENT);
    }
  } else if (wg < NLWG + NPWG) {
    const int p = wg - NLWG, bt = p / 5, vt = p % 5, bh = bt >> 1;
    {
      const f16x8* src = (const f16x8*)((const f16*)(ws + OFF_WOUT) + vt*8192);
      f16x8* dst = (f16x8*)wolds;
      for (int i = tid; i < 1024; i += 256) dst[i] = src[i];
    }
    __syncthreads();
    if (wv >= 2) return;                              // waves 2/3 idle after staging
    const int wp = (bt & 1)*2 + wv;                   // producer wave index feeding our rows
    const int v = vt*16 + nlane;
    const float bo = (v < VOC) ? b_out[v] : 0.0f;
    const int* sfL2 = F + (((4 + bh)*4 + wp)*32 + (lane & 31))*FPAD;
    int* pf = F + (768 + (bh*4 + wp)*5 + vt)*FPAD;
    const int bmb = bt*32 + wv*16;
    for (int t = 0; t < T_STEPS; ++t) {
      {
        int sat = (lane < 32) ? 0 : 1;
        int sp = 0;
        while (1) {
          if (!sat) {
            int vv = __hip_atomic_load(sfL2, __ATOMIC_RELAXED, __HIP_MEMORY_SCOPE_AGENT);
            if (vv >= t + 1) sat = 1;
          }
          if (__all(sat)) break;
          if (++sp > (1 << 22)) break;
          __builtin_amdgcn_s_sleep(1);
        }
      }
      const f16* hrow = hring + ((size_t)(2*DRING + (t & 7))*BATCH + bmb + nlane)*HID + ko;
      f16x8 af[16];
#pragma unroll
      for (int kc = 0; kc < 16; ++kc) af[kc] = ld16_sc(hrow + kc*32);
      wait_vm0();
#pragma unroll
      for (int kc = 0; kc < 16; ++kc) asm volatile("" : "+v"(af[kc]));
      f32x4 acc{0,0,0,0};
#pragma unroll
      for (int kc = 0; kc < 16; ++kc) {
        f16x8 w = *(const f16x8*)(wolds + ((kc*64 + lane) << 3));
        acc = __builtin_amdgcn_mfma_f32_16x16x32_f16(af[kc], w, acc, 0, 0, 0);
      }
      if (v < VOC) {
#pragma unroll
        for (int i = 0; i < 4; ++i) {
          int bidx = bmb + quad*4 + i;
          out[((size_t)bidx*T_STEPS + t)*VOC + v] = acc[i] + bo;
        }
      }
      if (lane == 0)                                  // loads consumed -> safe to recycle slot
        __hip_atomic_store(pf, t + 1, __ATOMIC_RELAXED, __HIP_MEMORY_SCOPE_AGENT);
    }
  }
}

extern "C" void kernel_launch(void* const* d_in, const int* in_sizes, int n_in,
                              void* d_out, int out_size, void* d_ws, size_t ws_size,
                              hipStream_t stream) {
  const int*   xseq  = (const int*)d_in[0];
  const float* emb   = (const float*)d_in[1];
  const float* w_ih  = (const float*)d_in[2];
  const float* w_hh  = (const float*)d_in[3];
  const float* b     = (const float*)d_in[4];
  const float* b_n   = (const float*)d_in[5];
  const float* w_out = (const float*)d_in[6];
  const float* b_out = (const float*)d_in[7];
  char* ws = (char*)d_ws;

  // zero flags + h ring (h[-1] = 0 initial state); re-done every call
  (void)hipMemsetAsync(d_ws, 0, OFF_HRING + HRING_BYTES, stream);
  hipLaunchKernelGGL(convert_kernel, dim3(4096), dim3(256), 0, stream,
                     emb, w_ih, w_hh, w_out, ws);
  hipLaunchKernelGGL(rnn_kernel, dim3(NLWG + NPWG), dim3(256), 0, stream,
                     xseq, b, b_n, b_out, (float*)d_out, ws);
}